// Round 2
// baseline (55.218 us; speedup 1.0000x reference)
//
#include <hip/hip_runtime.h>

// Analytic reduction of the FQCNN circuit (see derivation in round 0):
//   expval(Z_4) = (1/16) Re[ e^{ip0} (8 + 2e^{ip1} + 2e^{ip2}
//                                     + e^{ip3}(1+e^{ip1})(1+e^{ip2})) ]
// where (p0,p1,p2,p3) = (im[2j,2k], im[2j,2k+1], im[2j+1,2k], im[2j+1,2k+1]).
// U3_w provably does not affect the wire-4 marginal (controlled-U3s act
// unitarily on wires 5/6 per fixed config of the control wires).
//
// v2: 4 outputs per thread (one float4 store, 64 B of row loads per thread).
// Traffic: 3.15 MB read + 0.79 MB write total — launch-overhead dominated.

__device__ __forceinline__ float ev4(float p0, float p1, float p2, float p3) {
    float s0, c0, s1, c1, s2, c2, s3, c3;
    __sincosf(p0, &s0, &c0);
    __sincosf(p1, &s1, &c1);
    __sincosf(p2, &s2, &c2);
    __sincosf(p3, &s3, &c3);
    float ar = 1.0f + c1, ai = s1;          // (1 + e^{ip1})
    float br = 1.0f + c2, bi = s2;          // (1 + e^{ip2})
    float mr = ar * br - ai * bi;
    float mi = ar * bi + ai * br;
    float tr = c3 * mr - s3 * mi;           // * e^{ip3}
    float ti = c3 * mi + s3 * mr;
    float Sr = 8.0f + 2.0f * c1 + 2.0f * c2 + tr;
    float Si = 2.0f * s1 + 2.0f * s2 + ti;
    return (c0 * Sr - s0 * Si) * 0.0625f;
}

__global__ __launch_bounds__(256) void fqcnn_kernel(const float* __restrict__ x,
                                                    float* __restrict__ out,
                                                    int n_quads) {
    int t = blockIdx.x * blockDim.x + threadIdx.x;
    if (t >= n_quads) return;
    // Each thread: 4 horizontally-adjacent 2x2 patches (8 input cols).
    int kq  = t & 15;   // which group of 8 columns (16 per row)
    int rp  = t >> 4;   // img * 64 + j (output row id)
    int j   = rp & 63;
    int img = rp >> 6;  // b*3 + c, in [0, 48)

    const float* row0 = x + (((size_t)img * 128 + 2 * j) * 128) + 8 * kq;
    const float* row1 = row0 + 128;
    float4 a0 = *(const float4*)(row0);      // im[2j,   8k .. 8k+3]
    float4 a1 = *(const float4*)(row0 + 4);  // im[2j,   8k+4 .. 8k+7]
    float4 b0 = *(const float4*)(row1);      // im[2j+1, 8k .. 8k+3]
    float4 b1 = *(const float4*)(row1 + 4);

    float4 res;
    res.x = ev4(a0.x, a0.y, b0.x, b0.y);
    res.y = ev4(a0.z, a0.w, b0.z, b0.w);
    res.z = ev4(a1.x, a1.y, b1.x, b1.y);
    res.w = ev4(a1.z, a1.w, b1.z, b1.w);

    *(float4*)(out + (size_t)rp * 64 + 4 * kq) = res;
}

extern "C" void kernel_launch(void* const* d_in, const int* in_sizes, int n_in,
                              void* d_out, int out_size, void* d_ws, size_t ws_size,
                              hipStream_t stream) {
    const float* x = (const float*)d_in[0];   // [16,3,128,128]
    float* out = (float*)d_out;               // [16,3,64,64] = 196608 floats

    const int n_quads = 16 * 3 * 64 * 16;     // 49152 threads, 4 outputs each
    const int block = 256;
    const int grid = (n_quads + block - 1) / block;  // 192
    fqcnn_kernel<<<grid, block, 0, stream>>>(x, out, n_quads);
}